// Round 4
// baseline (373.774 us; speedup 1.0000x reference)
//
#include <hip/hip_runtime.h>

// Problem constants
#define B_   4
#define L_   4096
#define D_   1024
#define ROWS (B_ * L_)     // 16384
#define K2   (2 * D_)      // 2048
#define BLD  (ROWS * D_)   // 16777216
#define CH   64            // chunk length for scan
#define NC   64            // chunks per sequence

typedef __attribute__((ext_vector_type(8))) short s8v;   // 8 x bf16
typedef __attribute__((ext_vector_type(4))) float f4v;   // 4 x f32 acc

__device__ __forceinline__ unsigned short f2bf(float f) {
    unsigned int u = __float_as_uint(f);
    u += 0x7FFFu + ((u >> 16) & 1u);
    return (unsigned short)(u >> 16);
}
__device__ __forceinline__ float sigmoidf_(float v) {
    return 1.0f / (1.0f + __expf(-v));
}
__device__ __forceinline__ void llds16(const void* g, void* l) {
    __builtin_amdgcn_global_load_lds(
        (const __attribute__((address_space(1))) unsigned int*)(g),
        (__attribute__((address_space(3))) unsigned int*)(l),
        16, 0, 0);
}

// ---------------- preprocessing ----------------

// Fused: blocks [0,256) = per-chunk partial sums; blocks [256,4352) = W->bf16.
__global__ void prep1(const float4* __restrict__ x4, float4* __restrict__ part4,
                      const float4* __restrict__ W, ushort4* __restrict__ Wbf) {
    int bid = blockIdx.x;
    int t = threadIdx.x;
    if (bid < 256) {
        int c = bid & 63, b = bid >> 6;
        const float4* p = x4 + ((size_t)(b * L_ + c * CH) * 256 + t);
        float4 s; s.x = 0.f; s.y = 0.f; s.z = 0.f; s.w = 0.f;
#pragma unroll 8
        for (int i = 0; i < CH; ++i) {
            float4 v = p[(size_t)i * 256];
            s.x += v.x; s.y += v.y; s.z += v.z; s.w += v.w;
        }
        part4[(size_t)bid * 256 + t] = s;
    } else {
        int i = (bid - 256) * 256 + t;     // [0, 1048576)
        float4 v = W[i];
        ushort4 o; o.x = f2bf(v.x); o.y = f2bf(v.y); o.z = f2bf(v.z); o.w = f2bf(v.w);
        Wbf[i] = o;
    }
}

// Fused chunk-scan + apply: writes avg (float4) and bf16 A matrix [ROWS x 2048].
__global__ void apply_scan(const float4* __restrict__ x4, const float4* __restrict__ part4,
                           float4* __restrict__ avg4, ushort4* __restrict__ A4) {
    __shared__ float inv[CH];
    int bid = blockIdx.x;            // [0,256)
    int c = bid & 63, b = bid >> 6;
    int t = threadIdx.x;
    if (t < CH) inv[t] = 1.0f / (float)(c * CH + t + 1);

    float4 s; s.x = 0.f; s.y = 0.f; s.z = 0.f; s.w = 0.f;
    for (int cc = 0; cc < c; ++cc) {
        float4 v = part4[((size_t)(b * NC + cc)) * 256 + t];
        s.x += v.x; s.y += v.y; s.z += v.z; s.w += v.w;
    }
    __syncthreads();

    size_t row0 = (size_t)b * L_ + (size_t)c * CH;
    const float4* px = x4 + (row0 * 256 + t);
    float4*       pa = avg4 + (row0 * 256 + t);
    ushort4*      pA = A4 + (row0 * 512 + t);
#pragma unroll 4
    for (int i = 0; i < CH; ++i) {
        float4 v = px[(size_t)i * 256];
        s.x += v.x; s.y += v.y; s.z += v.z; s.w += v.w;
        float r = inv[i];
        float4 av; av.x = s.x * r; av.y = s.y * r; av.z = s.z * r; av.w = s.w * r;
        pa[(size_t)i * 256] = av;
        ushort4 ux; ux.x = f2bf(v.x);  ux.y = f2bf(v.y);  ux.z = f2bf(v.z);  ux.w = f2bf(v.w);
        ushort4 ua; ua.x = f2bf(av.x); ua.y = f2bf(av.y); ua.z = f2bf(av.z); ua.w = f2bf(av.w);
        pA[(size_t)i * 512]       = ux;
        pA[(size_t)i * 512 + 256] = ua;
    }
}

// ---------------- 8-wave phased GEMM + gating ----------------
// Block: 512 threads = 8 waves (4M x 2N). Output: 256 rows x 128 cols x 2 halves.
// BK=32. LDS: 4-buffer ring (128 KiB), 3-tile lead, counted vmcnt(8).
// R4: m201 barrier discipline. Raw s_barrier (NO compiler memory fences) so the
// backend can pipeline ds_reads/staging across phase boundaries; explicit
// "s_waitcnt lgkmcnt(0)" + sched_barrier(0) (rule #18) in front of each MFMA
// cluster; "memory"-clobbered counted vmcnt only once per tau. Epilogue drain:
// vmcnt(8) is a no-op once staging stops (tau>=61) -> use vmcnt(0) there
// (fixes a latent readiness race for tiles 62/63).
// LDS swizzle (R3, verified conflict-free): phys_byte = logical ^ (((row>>1)&3)<<4);
// staging applies inverse granule perm q ^ ((q>>3)&3) to the GLOBAL source.
__global__ __launch_bounds__(512, 2) void gemm_gated8(
        const unsigned short* __restrict__ Abf, const unsigned short* __restrict__ Wbf,
        const float* __restrict__ x, const float* __restrict__ avg,
        const float* __restrict__ bg, float* __restrict__ out) {
    __shared__ __attribute__((aligned(16))) unsigned short S[4 * 2 * 8192]; // 128 KiB

    const int t    = threadIdx.x;          // 0..511
    const int w    = t >> 6;               // 0..7
    const int lane = t & 63;
    const int wm = w >> 1, wn = w & 1;     // 4M x 2N wave grid
    const int quad = lane >> 4, lcol = lane & 15;

    const int bid = blockIdx.x;            // 512 blocks, 512%8==0 -> bijective
    const int swz = (bid & 7) * 64 + (bid >> 3);     // XCD-contiguous
    const int tileN = swz & 7, tileM = swz >> 3;
    const int row0 = tileM * 256, col0 = tileN * 128;

    f4v acc0[4][4], acc1[4][4];
#pragma unroll
    for (int i = 0; i < 4; ++i)
#pragma unroll
        for (int j = 0; j < 4; ++j)
#pragma unroll
            for (int r = 0; r < 4; ++r) { acc0[i][j][r] = 0.f; acc1[i][j][r] = 0.f; }

    // ---- staging precompute: thread t owns granules q = t and q = 512+t ----
    const int qA0 = t, qA1 = 512 + t;
    const int p0 = qA0 ^ ((qA0 >> 3) & 3);
    const int p1 = qA1 ^ ((qA1 >> 3) & 3);
    const int m0 = p0 >> 2, k0e = (p0 & 3) * 8;
    const int m1 = p1 >> 2, k1e = (p1 & 3) * 8;
    const unsigned short* gA0 = Abf + (size_t)(row0 + m0) * K2 + k0e;
    const unsigned short* gA1 = Abf + (size_t)(row0 + m1) * K2 + k1e;
    const unsigned short* gB0 = Wbf + (size_t)(col0 + (m0 & 127) + (m0 >> 7) * 1024) * K2 + k0e;
    const unsigned short* gB1 = Wbf + (size_t)(col0 + (m1 & 127) + (m1 >> 7) * 1024) * K2 + k1e;

    // ---- LDS read offsets (ushort index), swizzled: byte ^= ((row>>1)&3)<<4 ----
    int aoff[4], boff[2][4];
#pragma unroll
    for (int i = 0; i < 4; ++i) {
        int ar = wm * 64 + i * 16 + lcol;
        aoff[i] = ((ar * 64 + quad * 16) ^ (((ar >> 1) & 3) << 4)) >> 1;
    }
#pragma unroll
    for (int h = 0; h < 2; ++h)
#pragma unroll
        for (int j = 0; j < 4; ++j) {
            int br = h * 128 + wn * 64 + j * 16 + lcol;
            boff[h][j] = ((br * 64 + quad * 16) ^ (((br >> 1) & 3) << 4)) >> 1;
        }

    // ---- prologue: stage tiles 0,1,2 into buffers 0,1,2 ----
#pragma unroll
    for (int tt = 0; tt < 3; ++tt) {
        unsigned short* dA = S + tt * 16384;
        unsigned short* dB = S + tt * 16384 + 8192;
        llds16(gA0 + tt * 32, dA + qA0 * 8);
        llds16(gA1 + tt * 32, dA + qA1 * 8);
        llds16(gB0 + tt * 32, dB + qA0 * 8);
        llds16(gB1 + tt * 32, dB + qA1 * 8);
    }
    asm volatile("s_waitcnt vmcnt(8)" ::: "memory");  // tile 0 landed; 1,2 in flight
    __builtin_amdgcn_s_barrier();

    // ---- main loop: 64 K-tiles, 2 phases each (m201 cadence) ----
#pragma unroll 4
    for (int tau = 0; tau < 64; ++tau) {
        const unsigned short* bA = S + (tau & 3) * 16384;
        const unsigned short* bB = bA + 8192;
        const int st = tau + 3;
        unsigned short* dA = S + (st & 3) * 16384;
        unsigned short* dB = dA + 8192;
        const bool do_stage = st < 64;
        const int ko = st * 32;

        // ---- phase 1: A + B-half0 reads | stage A | barrier | MFMA acc0 ----
        s8v af[4], bf[4];
#pragma unroll
        for (int i = 0; i < 4; ++i) af[i] = *(const s8v*)(bA + aoff[i]);
#pragma unroll
        for (int j = 0; j < 4; ++j) bf[j] = *(const s8v*)(bB + boff[0][j]);
        if (do_stage) {
            llds16(gA0 + ko, dA + qA0 * 8);
            llds16(gA1 + ko, dA + qA1 * 8);
        }
        __builtin_amdgcn_s_barrier();
        asm volatile("s_waitcnt lgkmcnt(0)");
        __builtin_amdgcn_sched_barrier(0);
        __builtin_amdgcn_s_setprio(1);
#pragma unroll
        for (int i = 0; i < 4; ++i)
#pragma unroll
            for (int j = 0; j < 4; ++j)
                acc0[i][j] = __builtin_amdgcn_mfma_f32_16x16x32_bf16(af[i], bf[j], acc0[i][j], 0, 0, 0);
        __builtin_amdgcn_s_setprio(0);
        __builtin_amdgcn_s_barrier();

        // ---- phase 2: B-half1 reads | stage B | vmcnt | barrier | MFMA acc1 ----
        s8v bg2[4];
#pragma unroll
        for (int j = 0; j < 4; ++j) bg2[j] = *(const s8v*)(bB + boff[1][j]);
        if (do_stage) {
            llds16(gB0 + ko, dB + qA0 * 8);
            llds16(gB1 + ko, dB + qA1 * 8);
        }
        if (tau < 61) {
            asm volatile("s_waitcnt vmcnt(8)" ::: "memory");  // retire next tile's loads
        } else {
            asm volatile("s_waitcnt vmcnt(0)" ::: "memory");  // epilogue drain
        }
        __builtin_amdgcn_s_barrier();
        asm volatile("s_waitcnt lgkmcnt(0)");
        __builtin_amdgcn_sched_barrier(0);
        __builtin_amdgcn_s_setprio(1);
#pragma unroll
        for (int i = 0; i < 4; ++i)
#pragma unroll
            for (int j = 0; j < 4; ++j)
                acc1[i][j] = __builtin_amdgcn_mfma_f32_16x16x32_bf16(af[i], bg2[j], acc1[i][j], 0, 0, 0);
        __builtin_amdgcn_s_setprio(0);
        __builtin_amdgcn_s_barrier();
    }

    // ---- epilogue: gating in-register. C/D: col = lane&15, row = quad*4+reg ----
    float b1v[4], b2v[4];
#pragma unroll
    for (int j = 0; j < 4; ++j) {
        int cc = col0 + wn * 64 + j * 16 + lcol;
        b1v[j] = bg[cc];
        b2v[j] = bg[1024 + cc];
    }
#pragma unroll
    for (int i = 0; i < 4; ++i) {
#pragma unroll
        for (int j = 0; j < 4; ++j) {
            int rr = row0 + wm * 64 + i * 16 + quad * 4;
            int cc = col0 + wn * 64 + j * 16 + lcol;
#pragma unroll
            for (int r = 0; r < 4; ++r) {
                size_t off = (size_t)(rr + r) * D_ + cc;
                float gi = sigmoidf_(acc0[i][j][r] + b1v[j]);
                float gf = sigmoidf_(acc1[i][j][r] + b2v[j]);
                out[off] = gi * x[off] + gf * avg[off];
            }
        }
    }
}

extern "C" void kernel_launch(void* const* d_in, const int* in_sizes, int n_in,
                              void* d_out, int out_size, void* d_ws, size_t ws_size,
                              hipStream_t stream) {
    const float* x  = (const float*)d_in[0];   // [4,4096,1024]
    const float* W  = (const float*)d_in[1];   // [2048,2048]
    const float* bg = (const float*)d_in[2];   // [2048]
    float* out = (float*)d_out;                // [BLD gating | BLD avg]
    float* avg = out + (size_t)BLD;

    char* ws = (char*)d_ws;
    unsigned short* Abf = (unsigned short*)(ws);                      // 64 MB [16384 x 2048] bf16
    unsigned short* Wbf = (unsigned short*)(ws + (size_t)67108864);   //  8 MB [2048 x 2048] bf16
    float4*         prt = (float4*)(ws + (size_t)75497472);           //  1 MB [B x NC x D] f32

    prep1<<<dim3(4352), dim3(256), 0, stream>>>((const float4*)x, prt,
                                                (const float4*)W, (ushort4*)Wbf);
    apply_scan<<<dim3(256), dim3(256), 0, stream>>>((const float4*)x, prt,
                                                    (float4*)avg, (ushort4*)Abf);
    gemm_gated8<<<dim3(512), dim3(512), 0, stream>>>(Abf, Wbf, x, avg, bg, out);
}